// Round 4
// baseline (421.228 us; speedup 1.0000x reference)
//
#include <hip/hip_runtime.h>
#include <math.h>

// FeatureWeightNet v4 (MI355X / gfx950)  B=2, C=64, H=512, W=640.
// Kernel A (stencil): thread = 4 px x 8 ch (one full group) -> in-thread
//   group sum, zero LDS/barriers. Block = 256 thr = 64x8 px tile x 2 groups.
//   4 ch-pair blocks per tile (innermost in swizzle) cover 64 channels.
//   Writes acc (NT) + per-group mean to gsum [B,8,H,W] in d_ws.
// Kernel B (head): 8->16->8->1 MLP + sigmoid from gsum (or from acc if
//   ws_size too small).

typedef float f4 __attribute__((ext_vector_type(4)));
#define EPSV 1e-5f

template<bool WRITE_GSUM>
__global__ __launch_bounds__(256, 4) void fwn_stencil(
    const float* __restrict__ F,    // [B,64,H,W]
    const float* __restrict__ off,  // [B,18,H,W]
    float* __restrict__ accp,       // [B,64,H,W]
    float* __restrict__ gsum,       // [B,8,H,W]
    int H, int W)
{
    const int HW = H * W;

    // 5120 blocks = 8 XCDs * 640. Per XCD: contiguous logical range,
    // order = ch-pair fastest, then y, then (b,bx) strip.
    const int f = blockIdx.x;
    const int l = (f & 7) * 640 + (f >> 3);
    const int pair  = l & 3;
    const int by    = (l >> 2) & 63;
    const int strip = l >> 8;          // 0..19
    const int bx = strip % 10;
    const int b  = strip / 10;

    const int tid = threadIdx.x;
    const int q  = tid & 127;          // pixel quad: 16 x 8
    const int s  = tid >> 7;           // group within pair
    const int qx = q & 15, qy = q >> 4;
    const int w = bx * 64 + qx * 4;
    const int h = by * 8 + qy;
    const int g  = pair * 2 + s;       // group 0..7
    const int c0 = g * 8;

    // reflected rows for dy = {-4,-2,0,2,4}
    int rowoff[5];
    #pragma unroll
    for (int k = 0; k < 5; ++k) {
        int hh = h + 2 * k - 4;
        if (hh < 0) hh = -hh;
        if (hh >= H) hh = 2 * H - 2 - hh;
        rowoff[k] = hh * W;
    }

    const float* op = off + (size_t)b * 18 * HW + h * W + w;
    const float* Fb = F + (size_t)(b * 64 + c0) * HW;
    float* ab = accp + (size_t)(b * 64 + c0) * HW + h * W + w;

    f4 acc[8];
    #pragma unroll
    for (int i = 0; i < 8; ++i) acc[i] = (f4){0.f, 0.f, 0.f, 0.f};

    if (bx >= 1 && bx <= 8) {
        // interior: 3 aligned f4 loads/row serve wide(-4,0,4)+narrow(-2,0,2)
        #pragma unroll
        for (int r = 0; r < 5; ++r) {
            f4 wb[3], wn[3];
            if ((r & 1) == 0) {
                const int sy = r >> 1;
                #pragma unroll
                for (int sx = 0; sx < 3; ++sx)
                    wb[sx] = 0.5f * *(const f4*)(op + (size_t)(sy * 3 + sx) * HW);
            }
            if (r >= 1 && r <= 3) {
                const int sy = r - 1;
                #pragma unroll
                for (int sx = 0; sx < 3; ++sx)
                    wn[sx] = 0.5f * *(const f4*)(op + (size_t)(9 + sy * 3 + sx) * HW);
            }
            const int rbase = rowoff[r] + w - 4;
            #pragma unroll
            for (int i = 0; i < 8; ++i) {
                const float* cb = Fb + (size_t)i * HW + rbase;
                const f4 a0 = *(const f4*)(cb);
                const f4 a1 = *(const f4*)(cb + 4);
                const f4 a2 = *(const f4*)(cb + 8);
                if ((r & 1) == 0) {
                    acc[i] += wb[0] * a0;
                    acc[i] += wb[1] * a1;
                    acc[i] += wb[2] * a2;
                }
                if (r >= 1 && r <= 3) {
                    const f4 m0v = __builtin_shufflevector(a0, a1, 2, 3, 4, 5);
                    const f4 m2v = __builtin_shufflevector(a1, a2, 2, 3, 4, 5);
                    acc[i] += wn[0] * m0v;
                    acc[i] += wn[1] * a1;
                    acc[i] += wn[2] * m2v;
                }
            }
        }
    } else {
        // border: reflected scalar gathers
        int colidx[12];
        #pragma unroll
        for (int j = 0; j < 12; ++j) {
            int x = w - 4 + j;
            if (x < 0) x = -x;
            if (x >= W) x = 2 * W - 2 - x;
            colidx[j] = x;
        }
        #pragma unroll
        for (int r = 0; r < 5; ++r) {
            f4 wb[3], wn[3];
            if ((r & 1) == 0) {
                const int sy = r >> 1;
                #pragma unroll
                for (int sx = 0; sx < 3; ++sx)
                    wb[sx] = 0.5f * *(const f4*)(op + (size_t)(sy * 3 + sx) * HW);
            }
            if (r >= 1 && r <= 3) {
                const int sy = r - 1;
                #pragma unroll
                for (int sx = 0; sx < 3; ++sx)
                    wn[sx] = 0.5f * *(const f4*)(op + (size_t)(9 + sy * 3 + sx) * HW);
            }
            #pragma unroll
            for (int i = 0; i < 8; ++i) {
                const float* cb = Fb + (size_t)i * HW + rowoff[r];
                float e[12];
                #pragma unroll
                for (int j = 0; j < 12; ++j) e[j] = cb[colidx[j]];
                if ((r & 1) == 0) {
                    #pragma unroll
                    for (int sx = 0; sx < 3; ++sx)
                        #pragma unroll
                        for (int p = 0; p < 4; ++p)
                            acc[i][p] += wb[sx][p] * e[4 * sx + p];
                }
                if (r >= 1 && r <= 3) {
                    #pragma unroll
                    for (int sx = 0; sx < 3; ++sx)
                        #pragma unroll
                        for (int p = 0; p < 4; ++p)
                            acc[i][p] += wn[sx][p] * e[2 + 2 * sx + p];
                }
            }
        }
    }

    f4 gs = {0.f, 0.f, 0.f, 0.f};
    #pragma unroll
    for (int i = 0; i < 8; ++i) {
        __builtin_nontemporal_store(acc[i], (f4*)(ab + (size_t)i * HW));
        gs += acc[i];
    }
    if (WRITE_GSUM) {
        gs *= 0.125f;
        *(f4*)(gsum + (size_t)(b * 8 + g) * HW + h * W + w) = gs;  // keep in L2
    }
}

__device__ __forceinline__ void mlp4(
    const f4* xs,   // xs[8]: group means for 4 pixels
    const float* __restrict__ w0, const float* __restrict__ b0,
    const float* __restrict__ g0, const float* __restrict__ beta0,
    const float* __restrict__ m0, const float* __restrict__ v0,
    const float* __restrict__ w1, const float* __restrict__ b1,
    const float* __restrict__ g1, const float* __restrict__ beta1,
    const float* __restrict__ m1, const float* __restrict__ v1,
    const float* __restrict__ ws, const float* __restrict__ bs,
    f4& sv)
{
    #pragma unroll
    for (int p = 0; p < 4; ++p) {
        float y0[16];
        #pragma unroll
        for (int o = 0; o < 16; ++o) {
            const float s0 = g0[o] * rsqrtf(v0[o] + EPSV);
            float z = 0.f;
            #pragma unroll
            for (int i = 0; i < 8; ++i) z += w0[o * 8 + i] * xs[i][p];
            z = z * s0 + (b0[o] - m0[o]) * s0 + beta0[o];
            y0[o] = fmaxf(z, 0.f);
        }
        float y1[8];
        #pragma unroll
        for (int o = 0; o < 8; ++o) {
            const float s1 = g1[o] * rsqrtf(v1[o] + EPSV);
            float z = 0.f;
            #pragma unroll
            for (int i = 0; i < 16; ++i) z += w1[o * 16 + i] * y0[i];
            z = z * s1 + (b1[o] - m1[o]) * s1 + beta1[o];
            y1[o] = fmaxf(z, 0.f);
        }
        float sm = bs[0];
        #pragma unroll
        for (int i = 0; i < 8; ++i) sm += ws[i] * y1[i];
        sv[p] = 1.f / (1.f + __expf(-sm));
    }
}

// head from gsum (21 MB read, likely L2/L3-hot)
__global__ __launch_bounds__(256) void fwn_head(
    const float* __restrict__ gsum,
    const float* __restrict__ w0, const float* __restrict__ b0,
    const float* __restrict__ g0, const float* __restrict__ beta0,
    const float* __restrict__ m0, const float* __restrict__ v0,
    const float* __restrict__ w1, const float* __restrict__ b1,
    const float* __restrict__ g1, const float* __restrict__ beta1,
    const float* __restrict__ m1, const float* __restrict__ v1,
    const float* __restrict__ ws, const float* __restrict__ bs,
    float* __restrict__ sig, int HW)
{
    const int jq = blockIdx.x * 256 + threadIdx.x;   // quad index over B*HW/4
    const int qHW = HW >> 2;
    const int b = jq / qHW;
    const int pq = jq - b * qHW;
    const float* gp = gsum + (size_t)b * 8 * HW + pq * 4;
    f4 xs[8];
    #pragma unroll
    for (int g = 0; g < 8; ++g) xs[g] = *(const f4*)(gp + (size_t)g * HW);
    f4 sv;
    mlp4(xs, w0, b0, g0, beta0, m0, v0, w1, b1, g1, beta1, m1, v1, ws, bs, sv);
    *(f4*)(sig + (size_t)b * HW + pq * 4) = sv;
}

// fallback head: recompute group sums from acc (if d_ws too small)
__global__ __launch_bounds__(256) void fwn_head_acc(
    const float* __restrict__ accp,
    const float* __restrict__ w0, const float* __restrict__ b0,
    const float* __restrict__ g0, const float* __restrict__ beta0,
    const float* __restrict__ m0, const float* __restrict__ v0,
    const float* __restrict__ w1, const float* __restrict__ b1,
    const float* __restrict__ g1, const float* __restrict__ beta1,
    const float* __restrict__ m1, const float* __restrict__ v1,
    const float* __restrict__ ws, const float* __restrict__ bs,
    float* __restrict__ sig, int HW)
{
    const int jq = blockIdx.x * 256 + threadIdx.x;
    const int qHW = HW >> 2;
    const int b = jq / qHW;
    const int pq = jq - b * qHW;
    const float* ap = accp + (size_t)b * 64 * HW + pq * 4;
    f4 xs[8];
    #pragma unroll
    for (int g = 0; g < 8; ++g) {
        f4 t = (f4){0.f, 0.f, 0.f, 0.f};
        #pragma unroll
        for (int c = 0; c < 8; ++c)
            t += *(const f4*)(ap + (size_t)(g * 8 + c) * HW);
        xs[g] = t * 0.125f;
    }
    f4 sv;
    mlp4(xs, w0, b0, g0, beta0, m0, v0, w1, b1, g1, beta1, m1, v1, ws, bs, sv);
    *(f4*)(sig + (size_t)b * HW + pq * 4) = sv;
}

extern "C" void kernel_launch(void* const* d_in, const int* in_sizes, int n_in,
                              void* d_out, int out_size, void* d_ws, size_t ws_size,
                              hipStream_t stream) {
    const float* F    = (const float*)d_in[0];
    const float* off  = (const float*)d_in[1];
    const float* w0   = (const float*)d_in[2];
    const float* b0   = (const float*)d_in[3];
    const float* g0   = (const float*)d_in[4];
    const float* bt0  = (const float*)d_in[5];
    const float* m0   = (const float*)d_in[6];
    const float* v0   = (const float*)d_in[7];
    const float* w1   = (const float*)d_in[8];
    const float* b1   = (const float*)d_in[9];
    const float* g1   = (const float*)d_in[10];
    const float* bt1  = (const float*)d_in[11];
    const float* m1   = (const float*)d_in[12];
    const float* v1   = (const float*)d_in[13];
    const float* ws   = (const float*)d_in[14];
    const float* bs   = (const float*)d_in[15];

    const int B = 2, H = 512, W = 640;
    const int HW = H * W;
    float* sig  = (float*)d_out;                  // [B,H,W]
    float* accp = sig + (size_t)B * HW;           // [B,64,H,W]
    float* gsum = (float*)d_ws;                   // [B,8,H,W] = 20.97 MB

    const size_t gsum_bytes = (size_t)B * 8 * HW * sizeof(float);
    const int nq = (B * HW) / 4;                  // 163840 -> 640 blocks exact

    if (ws_size >= gsum_bytes) {
        fwn_stencil<true><<<dim3(5120), dim3(256), 0, stream>>>(
            F, off, accp, gsum, H, W);
        fwn_head<<<dim3(nq / 256), dim3(256), 0, stream>>>(
            gsum, w0, b0, g0, bt0, m0, v0, w1, b1, g1, bt1, m1, v1, ws, bs,
            sig, HW);
    } else {
        fwn_stencil<false><<<dim3(5120), dim3(256), 0, stream>>>(
            F, off, accp, gsum, H, W);
        fwn_head_acc<<<dim3(nq / 256), dim3(256), 0, stream>>>(
            accp, w0, b0, g0, bt0, m0, v0, w1, b1, g1, bt1, m1, v1, ws, bs,
            sig, HW);
    }
}

// Round 5
// 367.848 us; speedup vs baseline: 1.1451x; 1.1451x over previous
//
#include <hip/hip_runtime.h>
#include <math.h>

// FeatureWeightNet v5 (MI355X / gfx950)  B=2, C=64, H=512, W=640.
// Stencil: thread = 4px quad x ALL 64 channels (8 octets of 8).
//   Block = 256 thr = 64x16 px tile. Grid = 640 blocks (whole grid
//   co-resident -> halo + offsets served from L2/L3; proven in R2: 180 MB).
//   Inner loop = R4's direct-f4 + shufflevector form (no array staging ->
//   ILP; R2's rb[] serialization was the latency killer).
//   Offsets re-read per octet from L2 (asm pointer-blind stops LLVM from
//   hoisting 30 f4 = 120 VGPR of loop-invariant loads).
// Head: 8->16->8->1 MLP + sigmoid from gsum[B,8,H,W] (d_ws), acc fallback.

typedef float f4 __attribute__((ext_vector_type(4)));
#define EPSV 1e-5f

__global__ __launch_bounds__(256, 2) void fwn_stencil(
    const float* __restrict__ F,    // [B,64,H,W]
    const float* __restrict__ off,  // [B,18,H,W]
    float* __restrict__ accp,       // [B,64,H,W]
    float* __restrict__ gsum,       // [B,8,H,W] (may be null -> skip)
    int H, int W, int write_gsum)
{
    const int HW = H * W;

    // 640 blocks = 8 XCDs * 80; y-fastest logical order per XCD strip.
    const int f = blockIdx.x;
    const int l = (f & 7) * 80 + (f >> 3);
    const int by = l & 31;             // 32 y-tiles of 16 rows
    const int rest = l >> 5;           // 0..19
    const int bx = rest % 10;          // 10 x-tiles of 64 px
    const int b  = rest / 10;

    const int tid = threadIdx.x;
    const int qx = tid & 15;
    const int ry = tid >> 4;           // 0..15
    const int w = bx * 64 + qx * 4;
    const int h = by * 16 + ry;

    // reflected rows for dy = {-4,-2,0,2,4}
    int rowoff[5];
    #pragma unroll
    for (int k = 0; k < 5; ++k) {
        int hh = h + 2 * k - 4;
        if (hh < 0) hh = -hh;
        if (hh >= H) hh = 2 * H - 2 - hh;
        rowoff[k] = hh * W;
    }

    const float* op = off + (size_t)b * 18 * HW + h * W + w;
    const float* Fb = F + (size_t)b * 64 * HW;
    float* ab = accp + (size_t)b * 64 * HW + h * W + w;

    const bool interior = (bx >= 1) && (bx <= 8);

    int colidx[12];
    if (!interior) {
        #pragma unroll
        for (int j = 0; j < 12; ++j) {
            int x = w - 4 + j;
            if (x < 0) x = -x;
            if (x >= W) x = 2 * W - 2 - x;
            colidx[j] = x;
        }
    }

    #pragma unroll 1                    // keep octets separate (blind works)
    for (int oct = 0; oct < 8; ++oct) {
        const float* cb0 = Fb + (size_t)(oct * 8) * HW;
        f4 acc[8];
        #pragma unroll
        for (int i = 0; i < 8; ++i) acc[i] = (f4){0.f, 0.f, 0.f, 0.f};

        if (interior) {
            #pragma unroll
            for (int r = 0; r < 5; ++r) {
                const float* opr = op;
                asm volatile("" : "+v"(opr));   // opaque: force per-iter reload
                f4 wb[3], wn[3];
                if ((r & 1) == 0) {
                    const int sy = r >> 1;
                    #pragma unroll
                    for (int sx = 0; sx < 3; ++sx)
                        wb[sx] = 0.5f * *(const f4*)(opr + (size_t)(sy * 3 + sx) * HW);
                }
                if (r >= 1 && r <= 3) {
                    const int sy = r - 1;
                    #pragma unroll
                    for (int sx = 0; sx < 3; ++sx)
                        wn[sx] = 0.5f * *(const f4*)(opr + (size_t)(9 + sy * 3 + sx) * HW);
                }
                const int rbase = rowoff[r] + w - 4;
                #pragma unroll
                for (int i = 0; i < 8; ++i) {
                    const float* cb = cb0 + (size_t)i * HW + rbase;
                    const f4 a0 = *(const f4*)(cb);
                    const f4 a1 = *(const f4*)(cb + 4);
                    const f4 a2 = *(const f4*)(cb + 8);
                    if ((r & 1) == 0) {
                        acc[i] += wb[0] * a0;
                        acc[i] += wb[1] * a1;
                        acc[i] += wb[2] * a2;
                    }
                    if (r >= 1 && r <= 3) {
                        const f4 m0v = __builtin_shufflevector(a0, a1, 2, 3, 4, 5);
                        const f4 m2v = __builtin_shufflevector(a1, a2, 2, 3, 4, 5);
                        acc[i] += wn[0] * m0v;
                        acc[i] += wn[1] * a1;
                        acc[i] += wn[2] * m2v;
                    }
                }
            }
        } else {
            #pragma unroll
            for (int r = 0; r < 5; ++r) {
                const float* opr = op;
                asm volatile("" : "+v"(opr));
                f4 wb[3], wn[3];
                if ((r & 1) == 0) {
                    const int sy = r >> 1;
                    #pragma unroll
                    for (int sx = 0; sx < 3; ++sx)
                        wb[sx] = 0.5f * *(const f4*)(opr + (size_t)(sy * 3 + sx) * HW);
                }
                if (r >= 1 && r <= 3) {
                    const int sy = r - 1;
                    #pragma unroll
                    for (int sx = 0; sx < 3; ++sx)
                        wn[sx] = 0.5f * *(const f4*)(opr + (size_t)(9 + sy * 3 + sx) * HW);
                }
                #pragma unroll
                for (int i = 0; i < 8; ++i) {
                    const float* cb = cb0 + (size_t)i * HW + rowoff[r];
                    float e[12];
                    #pragma unroll
                    for (int j = 0; j < 12; ++j) e[j] = cb[colidx[j]];
                    if ((r & 1) == 0) {
                        #pragma unroll
                        for (int sx = 0; sx < 3; ++sx)
                            #pragma unroll
                            for (int p = 0; p < 4; ++p)
                                acc[i][p] += wb[sx][p] * e[4 * sx + p];
                    }
                    if (r >= 1 && r <= 3) {
                        #pragma unroll
                        for (int sx = 0; sx < 3; ++sx)
                            #pragma unroll
                            for (int p = 0; p < 4; ++p)
                                acc[i][p] += wn[sx][p] * e[2 + 2 * sx + p];
                    }
                }
            }
        }

        f4 gs = {0.f, 0.f, 0.f, 0.f};
        #pragma unroll
        for (int i = 0; i < 8; ++i) {
            __builtin_nontemporal_store(acc[i], (f4*)(ab + (size_t)(oct * 8 + i) * HW));
            gs += acc[i];
        }
        if (write_gsum)
            *(f4*)(gsum + (size_t)(b * 8 + oct) * HW + h * W + w) = gs * 0.125f;
    }
}

__device__ __forceinline__ void mlp4(
    const f4* xs,
    const float* __restrict__ w0, const float* __restrict__ b0,
    const float* __restrict__ g0, const float* __restrict__ beta0,
    const float* __restrict__ m0, const float* __restrict__ v0,
    const float* __restrict__ w1, const float* __restrict__ b1,
    const float* __restrict__ g1, const float* __restrict__ beta1,
    const float* __restrict__ m1, const float* __restrict__ v1,
    const float* __restrict__ ws, const float* __restrict__ bs,
    f4& sv)
{
    #pragma unroll
    for (int p = 0; p < 4; ++p) {
        float y0[16];
        #pragma unroll
        for (int o = 0; o < 16; ++o) {
            const float s0 = g0[o] * rsqrtf(v0[o] + EPSV);
            float z = 0.f;
            #pragma unroll
            for (int i = 0; i < 8; ++i) z += w0[o * 8 + i] * xs[i][p];
            z = z * s0 + (b0[o] - m0[o]) * s0 + beta0[o];
            y0[o] = fmaxf(z, 0.f);
        }
        float y1[8];
        #pragma unroll
        for (int o = 0; o < 8; ++o) {
            const float s1 = g1[o] * rsqrtf(v1[o] + EPSV);
            float z = 0.f;
            #pragma unroll
            for (int i = 0; i < 16; ++i) z += w1[o * 16 + i] * y0[i];
            z = z * s1 + (b1[o] - m1[o]) * s1 + beta1[o];
            y1[o] = fmaxf(z, 0.f);
        }
        float sm = bs[0];
        #pragma unroll
        for (int i = 0; i < 8; ++i) sm += ws[i] * y1[i];
        sv[p] = 1.f / (1.f + __expf(-sm));
    }
}

__global__ __launch_bounds__(256) void fwn_head(
    const float* __restrict__ gsum,
    const float* __restrict__ w0, const float* __restrict__ b0,
    const float* __restrict__ g0, const float* __restrict__ beta0,
    const float* __restrict__ m0, const float* __restrict__ v0,
    const float* __restrict__ w1, const float* __restrict__ b1,
    const float* __restrict__ g1, const float* __restrict__ beta1,
    const float* __restrict__ m1, const float* __restrict__ v1,
    const float* __restrict__ ws, const float* __restrict__ bs,
    float* __restrict__ sig, int HW)
{
    const int jq = blockIdx.x * 256 + threadIdx.x;
    const int qHW = HW >> 2;
    const int b = jq / qHW;
    const int pq = jq - b * qHW;
    const float* gp = gsum + (size_t)b * 8 * HW + pq * 4;
    f4 xs[8];
    #pragma unroll
    for (int g = 0; g < 8; ++g) xs[g] = *(const f4*)(gp + (size_t)g * HW);
    f4 sv;
    mlp4(xs, w0, b0, g0, beta0, m0, v0, w1, b1, g1, beta1, m1, v1, ws, bs, sv);
    *(f4*)(sig + (size_t)b * HW + pq * 4) = sv;
}

__global__ __launch_bounds__(256) void fwn_head_acc(
    const float* __restrict__ accp,
    const float* __restrict__ w0, const float* __restrict__ b0,
    const float* __restrict__ g0, const float* __restrict__ beta0,
    const float* __restrict__ m0, const float* __restrict__ v0,
    const float* __restrict__ w1, const float* __restrict__ b1,
    const float* __restrict__ g1, const float* __restrict__ beta1,
    const float* __restrict__ m1, const float* __restrict__ v1,
    const float* __restrict__ ws, const float* __restrict__ bs,
    float* __restrict__ sig, int HW)
{
    const int jq = blockIdx.x * 256 + threadIdx.x;
    const int qHW = HW >> 2;
    const int b = jq / qHW;
    const int pq = jq - b * qHW;
    const float* ap = accp + (size_t)b * 64 * HW + pq * 4;
    f4 xs[8];
    #pragma unroll
    for (int g = 0; g < 8; ++g) {
        f4 t = (f4){0.f, 0.f, 0.f, 0.f};
        #pragma unroll
        for (int c = 0; c < 8; ++c)
            t += *(const f4*)(ap + (size_t)(g * 8 + c) * HW);
        xs[g] = t * 0.125f;
    }
    f4 sv;
    mlp4(xs, w0, b0, g0, beta0, m0, v0, w1, b1, g1, beta1, m1, v1, ws, bs, sv);
    *(f4*)(sig + (size_t)b * HW + pq * 4) = sv;
}

extern "C" void kernel_launch(void* const* d_in, const int* in_sizes, int n_in,
                              void* d_out, int out_size, void* d_ws, size_t ws_size,
                              hipStream_t stream) {
    const float* F    = (const float*)d_in[0];
    const float* off  = (const float*)d_in[1];
    const float* w0   = (const float*)d_in[2];
    const float* b0   = (const float*)d_in[3];
    const float* g0   = (const float*)d_in[4];
    const float* bt0  = (const float*)d_in[5];
    const float* m0   = (const float*)d_in[6];
    const float* v0   = (const float*)d_in[7];
    const float* w1   = (const float*)d_in[8];
    const float* b1   = (const float*)d_in[9];
    const float* g1   = (const float*)d_in[10];
    const float* bt1  = (const float*)d_in[11];
    const float* m1   = (const float*)d_in[12];
    const float* v1   = (const float*)d_in[13];
    const float* ws   = (const float*)d_in[14];
    const float* bs   = (const float*)d_in[15];

    const int B = 2, H = 512, W = 640;
    const int HW = H * W;
    float* sig  = (float*)d_out;                  // [B,H,W]
    float* accp = sig + (size_t)B * HW;           // [B,64,H,W]
    float* gsum = (float*)d_ws;                   // [B,8,H,W] = 20.97 MB

    const size_t gsum_bytes = (size_t)B * 8 * HW * sizeof(float);
    const int use_ws = (ws_size >= gsum_bytes) ? 1 : 0;
    const int nq = (B * HW) / 4;                  // 163840 -> 640 blocks exact

    fwn_stencil<<<dim3(640), dim3(256), 0, stream>>>(
        F, off, accp, gsum, H, W, use_ws);
    if (use_ws) {
        fwn_head<<<dim3(nq / 256), dim3(256), 0, stream>>>(
            gsum, w0, b0, g0, bt0, m0, v0, w1, b1, g1, bt1, m1, v1, ws, bs,
            sig, HW);
    } else {
        fwn_head_acc<<<dim3(nq / 256), dim3(256), 0, stream>>>(
            accp, w0, b0, g0, bt0, m0, v0, w1, b1, g1, bt1, m1, v1, ws, bs,
            sig, HW);
    }
}